// Round 4
// baseline (211.124 us; speedup 1.0000x reference)
//
#include <hip/hip_runtime.h>
#include <math.h>

#define NNODE 32768     // B*T*N
#define NEDGE 524288    // NNODE * DEG
#define DD 64           // feature dim D
#define EPS_G 65536     // edges per structure (NEDGE/8)

typedef float  f32x4 __attribute__((ext_vector_type(4)));
typedef short  s16x8 __attribute__((ext_vector_type(8)));

__device__ __forceinline__ float silu_f(float x) {
    return x / (1.0f + __expf(-x));
}
// f32 -> bf16 bits, round-to-nearest-even
__device__ __forceinline__ unsigned short bf16r(float f) {
    unsigned u = __float_as_uint(f);
    unsigned r = (u + 0x7FFFu + ((u >> 16) & 1u)) >> 16;
    return (unsigned short)r;
}

// pos = x * v_mask + x1 * (1 - v_mask)
__global__ __launch_bounds__(256) void k_prep(
    const float* __restrict__ x, const float* __restrict__ x1,
    const float* __restrict__ vm, float* __restrict__ pos)
{
    int i = blockIdx.x * 256 + threadIdx.x;      // 128 blocks
    float m = vm[i];
    #pragma unroll
    for (int c = 0; c < 3; ++c)
        pos[i*3+c] = x[i*3+c]*m + x1[i*3+c]*(1.0f-m);
}

// base[b][ch] = sum_k h_b[k] * (Wm[k][ch] + Wm[64+k][ch]),  h_b[k]=Wsp[k]+t_b*Wt[k]
__global__ void k_base(const float* __restrict__ Wsp, const float* __restrict__ Wt,
                       const float* __restrict__ Wm, const float* __restrict__ tarr,
                       float* __restrict__ base_ws)
{
    int ch = threadIdx.x;            // 64 threads
    float t0 = tarr[0], t1 = tarr[1];
    float aA = 0.0f, aB = 0.0f;
    for (int k = 0; k < DD; ++k) {
        float w = Wm[k*DD + ch] + Wm[(DD+k)*DD + ch];
        aA = fmaf(Wsp[k] + t0*Wt[k], w, aA);
        aB = fmaf(Wsp[k] + t1*Wt[k], w, aB);
    }
    base_ws[ch]      = aA;
    base_ws[DD + ch] = aB;
}

// histogram of dst (cnt pre-zeroed by memset). XCD-mapped per structure.
__global__ __launch_bounds__(256) void k_hist(
    const int* __restrict__ ei, int* __restrict__ cnt)
{
    int g = blockIdx.x & 7;
    int e = g * EPS_G + (blockIdx.x >> 3) * 256 + threadIdx.x;  // 2048 blocks
    atomicAdd(&cnt[ei[NEDGE + e]], 1);
}

// exclusive scan of cnt[32768] -> cursor[32768]. One block, 1024 threads.
__global__ __launch_bounds__(1024) void k_scan(
    const int* __restrict__ cnt, int* __restrict__ cursor)
{
    __shared__ int buf[2][1024];
    const int tid = threadIdx.x;
    const int base = tid * 32;
    int loc[32];
    int s = 0;
    #pragma unroll
    for (int j = 0; j < 32; ++j) { int c = cnt[base+j]; loc[j] = c; s += c; }
    buf[0][tid] = s;
    __syncthreads();
    int pp = 0;
    for (int off = 1; off < 1024; off <<= 1) {
        int v = buf[pp][tid];
        if (tid >= off) v += buf[pp][tid - off];
        buf[pp^1][tid] = v;
        __syncthreads();
        pp ^= 1;
    }
    int ex = tid ? buf[pp][tid-1] : 0;
    #pragma unroll
    for (int j = 0; j < 32; ++j) { cursor[base+j] = ex; ex += loc[j]; }
}

// compute geometry once + counting-sort scatter by dst.
// srec[slot] = {ev0,ev1,ev2,len}; sdst[slot] = dst.
__global__ __launch_bounds__(256) void k_sortgeo(
    const int* __restrict__ ei, const int* __restrict__ tj,
    const float* __restrict__ pos, const float* __restrict__ cell,
    int* __restrict__ cursor, float4* __restrict__ srec, int* __restrict__ sdst)
{
    int g = blockIdx.x & 7;
    int e = g * EPS_G + (blockIdx.x >> 3) * 256 + threadIdx.x;  // 2048 blocks
    int src = ei[e];
    int dst = ei[NEDGE + e];
    const float* cl = cell + g*9;
    float c00=cl[0],c01=cl[1],c02=cl[2],c10=cl[3],c11=cl[4],c12=cl[5],c20=cl[6],c21=cl[7],c22=cl[8];
    float tj0 = (float)tj[e*3+0], tj1 = (float)tj[e*3+1], tj2 = (float)tj[e*3+2];
    float ev0 = pos[dst*3+0] - pos[src*3+0] + tj0*c00 + tj1*c10 + tj2*c20;
    float ev1 = pos[dst*3+1] - pos[src*3+1] + tj0*c01 + tj1*c11 + tj2*c21;
    float ev2 = pos[dst*3+2] - pos[src*3+2] + tj0*c02 + tj1*c12 + tj2*c22;
    float len = sqrtf(ev0*ev0 + ev1*ev1 + ev2*ev2 + 1e-12f);
    int slot = atomicAdd(&cursor[dst], 1);
    srec[slot] = (float4){ev0, ev1, ev2, len};
    sdst[slot] = dst;
}

// MFMA edge kernel on dst-sorted edges. Wave = 64-edge tile.
// PASS==1: segmented-reduce msg over equal-dst runs -> one atomic per run/channel.
// PASS==2: outacc[dst][c] += ev[c]*(msg . g[dst])
template<int PASS>
__global__ __launch_bounds__(256) void k_edge_sorted(
    const float4* __restrict__ srec, const int* __restrict__ sdst,
    const float* __restrict__ We, const float* __restrict__ Wm,
    const float* __restrict__ base_ws,
    float* agg, const float* __restrict__ gbuf, float* __restrict__ outacc)
{
    const int lane = threadIdx.x & 63;
    const int warp = threadIdx.x >> 6;
    const int lo16 = lane & 15;
    const int hi   = lane >> 4;
    const int g    = blockIdx.x & 7;   // structure == XCD slot (1024 tiles each)
    const int tile = g * 1024 + (blockIdx.x >> 3) * 4 + warp;
    const int e0   = tile * 64;

    // per-wave LDS: edge4 f4[64] @0 | dstl int[64] @1024 | ea bf16[16][72] @1280
    //               msglds f32[16][65] @3584  -> 7744 B, pad to 7936
    __shared__ __align__(16) char smem_all[4][7936];
    char* my = smem_all[warp];
    float4*         edge4  = (float4*)my;
    int*            dstl   = (int*)(my + 1024);
    unsigned short* ealds  = (unsigned short*)(my + 1280);
    float*          msglds = (float*)(my + 3584);

    // ---- init: W3 B-fragments (bf16), W_edge column, base vector ----
    s16x8 bfr[4][2];
    #pragma unroll
    for (int t2 = 0; t2 < 4; ++t2)
        #pragma unroll
        for (int s = 0; s < 2; ++s) {
            s16x8 f;
            #pragma unroll
            for (int j = 0; j < 8; ++j) {
                int k = s*32 + hi*8 + j;
                f[j] = (short)bf16r(Wm[(128 + k)*DD + t2*16 + lo16]);
            }
            bfr[t2][s] = f;
        }
    const float we0 = We[0*DD+lane], we1 = We[1*DD+lane];
    const float we2 = We[2*DD+lane], we3 = We[3*DD+lane];
    const bool  sb  = (g >> 2) != 0;          // batch
    const float bv0 = base_ws[sb*DD + 0*16+lo16];
    const float bv1 = base_ws[sb*DD + 1*16+lo16];
    const float bv2 = base_ws[sb*DD + 2*16+lo16];
    const float bv3 = base_ws[sb*DD + 3*16+lo16];

    // ---- load sorted records (coalesced) ----
    edge4[lane] = srec[e0 + lane];
    dstl[lane]  = sdst[e0 + lane];

    // ---- 4 sub-tiles of 16 edges ----
    #pragma unroll
    for (int i = 0; i < 4; ++i) {
        __syncthreads();     // i=0: edge4/dstl visible; i>0: ealds/msglds reusable
        #pragma unroll
        for (int ee = 0; ee < 16; ++ee) {
            float4 q = edge4[i*16 + ee];               // uniform -> broadcast
            float v = q.x*we0 + q.y*we1 + q.z*we2 + q.w*we3;
            ealds[ee*72 + lane] = bf16r(silu_f(v));
        }
        __syncthreads();     // ea tile visible

        const unsigned short* arow = ealds + lo16*72 + hi*8;
        s16x8 a0 = *(const s16x8*)(arow);
        s16x8 a1 = *(const s16x8*)(arow + 32);

        if (PASS == 1) {
            #pragma unroll
            for (int t2 = 0; t2 < 4; ++t2) {
                f32x4 acc = {0.f, 0.f, 0.f, 0.f};
                acc = __builtin_amdgcn_mfma_f32_16x16x32_bf16(a0, bfr[t2][0], acc, 0, 0, 0);
                acc = __builtin_amdgcn_mfma_f32_16x16x32_bf16(a1, bfr[t2][1], acc, 0, 0, 0);
                const float bvt = t2==0 ? bv0 : t2==1 ? bv1 : t2==2 ? bv2 : bv3;
                #pragma unroll
                for (int r = 0; r < 4; ++r)
                    msglds[(hi*4+r)*65 + t2*16 + lo16] = silu_f(acc[r] + bvt);
            }
            __syncthreads();  // msg tile visible
            // segmented reduce over equal-dst runs (lane = channel)
            float s = 0.0f;
            int curn = dstl[i*16];
            #pragma unroll
            for (int r = 0; r < 16; ++r) {
                int nd  = dstl[i*16 + r];               // uniform broadcast
                float v = msglds[r*65 + lane];
                if (r > 0 && nd != curn) {               // wave-uniform branch
                    atomicAdd(&agg[curn*DD + lane], s);
                    s = 0.0f; curn = nd;
                }
                s += v;
            }
            atomicAdd(&agg[curn*DD + lane], s);
        } else {
            int dr0 = dstl[i*16 + hi*4 + 0];
            int dr1 = dstl[i*16 + hi*4 + 1];
            int dr2 = dstl[i*16 + hi*4 + 2];
            int dr3 = dstl[i*16 + hi*4 + 3];
            float p0 = 0.f, p1 = 0.f, p2 = 0.f, p3 = 0.f;
            #pragma unroll
            for (int t2 = 0; t2 < 4; ++t2) {
                f32x4 acc = {0.f, 0.f, 0.f, 0.f};
                acc = __builtin_amdgcn_mfma_f32_16x16x32_bf16(a0, bfr[t2][0], acc, 0, 0, 0);
                acc = __builtin_amdgcn_mfma_f32_16x16x32_bf16(a1, bfr[t2][1], acc, 0, 0, 0);
                const float bvt = t2==0 ? bv0 : t2==1 ? bv1 : t2==2 ? bv2 : bv3;
                const int   chc = t2*16 + lo16;
                #pragma unroll
                for (int r = 0; r < 4; ++r) {
                    const int drr = r==0 ? dr0 : r==1 ? dr1 : r==2 ? dr2 : dr3;
                    float msg = silu_f(acc[r] + bvt);
                    float pm  = msg * gbuf[drr*DD + chc];
                    if (r==0) p0 += pm; else if (r==1) p1 += pm;
                    else if (r==2) p2 += pm; else p3 += pm;
                }
            }
            #pragma unroll
            for (int st = 1; st < 16; st <<= 1) {
                p0 += __shfl_xor(p0, st, 64);
                p1 += __shfl_xor(p1, st, 64);
                p2 += __shfl_xor(p2, st, 64);
                p3 += __shfl_xor(p3, st, 64);
            }
            if (lo16 < 12) {
                int rr = lo16 / 3, c = lo16 % 3;
                float dsel = rr==0 ? p0 : rr==1 ? p1 : rr==2 ? p2 : p3;
                int   drow = rr==0 ? dr0 : rr==1 ? dr1 : rr==2 ? dr2 : dr3;
                int   lrow = i*16 + hi*4 + rr;
                float evc = *(const float*)(my + lrow*16 + c*4);
                atomicAdd(&outacc[drow*3 + c], evc * dsel);
            }
        }
    }
}

// Per-node gate: g[n][d] = silu(h_b[d] + silu(agg[n]@W_upd)[d]) * w_dec[d]  (in place)
__global__ __launch_bounds__(256) void k_node(
    float* aggg,
    const float* __restrict__ t, const float* __restrict__ Wsp,
    const float* __restrict__ Wt, const float* __restrict__ Wu,
    const float* __restrict__ wdec)
{
    const int lane = threadIdx.x & 63;
    const int warp = threadIdx.x >> 6;
    const int g    = blockIdx.x & 7;
    const int wloc = (blockIdx.x >> 3) * 4 + warp;     // 0..1023 within structure

    float wu[DD];
    #pragma unroll
    for (int k = 0; k < DD; ++k) wu[k] = Wu[k*DD + lane];
    const float wsl = Wsp[lane], wtl = Wt[lane], wd = wdec[lane];
    const float tb = (g >> 2) == 0 ? t[0] : t[1];

    #pragma unroll
    for (int j = 0; j < 4; ++j) {
        int nd = g*4096 + wloc + j*1024;
        float a = aggg[nd*DD + lane];
        unsigned ab = __float_as_uint(a);
        float acc = 0.0f;
        #pragma unroll
        for (int k = 0; k < DD; ++k) {
            float ak = __uint_as_float(__builtin_amdgcn_readlane(ab, k));
            acc = fmaf(ak, wu[k], acc);
        }
        float hn = wsl + tb * wtl + silu_f(acc);
        aggg[nd*DD + lane] = silu_f(hn) * wd;
    }
}

// out = outacc * v_mask
__global__ __launch_bounds__(256) void k_final(
    const float* __restrict__ outacc, const float* __restrict__ vm,
    float* __restrict__ out)
{
    int i = blockIdx.x * 256 + threadIdx.x;   // 384 blocks
    out[i] = outacc[i] * vm[i/3];
}

extern "C" void kernel_launch(void* const* d_in, const int* in_sizes, int n_in,
                              void* d_out, int out_size, void* d_ws, size_t ws_size,
                              hipStream_t stream) {
    const float* x    = (const float*)d_in[0];
    const float* t    = (const float*)d_in[1];
    const float* cell = (const float*)d_in[2];
    const float* x1   = (const float*)d_in[3];
    const float* vm   = (const float*)d_in[4];
    const float* Wsp  = (const float*)d_in[5];
    const float* Wt   = (const float*)d_in[6];
    const float* We   = (const float*)d_in[7];
    const float* Wm   = (const float*)d_in[8];
    const float* Wu   = (const float*)d_in[9];
    const float* wdec = (const float*)d_in[10];
    const int*   ei   = (const int*)d_in[11];
    const int*   tj   = (const int*)d_in[12];
    float* out = (float*)d_out;

    // ws floats: pos[98304] | agg[2097152] | outacc[98304] | base[128]
    //            cnt[32768] | cursor[32768] | sdst[524288] | srec[4*524288]
    float* ws      = (float*)d_ws;
    float* pos     = ws;
    float* agg     = ws + 98304;
    float* outacc  = agg + 2097152;
    float* base_ws = outacc + 98304;
    int*   cnt     = (int*)(base_ws + 128);
    int*   cursor  = cnt + 32768;
    int*   sdst    = cursor + 32768;
    float4* srec   = (float4*)(sdst + 524288);   // 16B-aligned (offset 11550848 B)

    hipMemsetAsync(agg, 0, 2097152*sizeof(float), stream);
    hipMemsetAsync(outacc, 0, 98304*sizeof(float), stream);
    hipMemsetAsync(cnt, 0, 32768*sizeof(int), stream);

    k_prep<<<128, 256, 0, stream>>>(x, x1, vm, pos);
    k_base<<<1, 64, 0, stream>>>(Wsp, Wt, Wm, t, base_ws);
    k_hist<<<2048, 256, 0, stream>>>(ei, cnt);
    k_scan<<<1, 1024, 0, stream>>>(cnt, cursor);
    k_sortgeo<<<2048, 256, 0, stream>>>(ei, tj, pos, cell, cursor, srec, sdst);
    k_edge_sorted<1><<<2048, 256, 0, stream>>>(srec, sdst, We, Wm, base_ws,
                                               agg, nullptr, nullptr);
    k_node<<<2048, 256, 0, stream>>>(agg, t, Wsp, Wt, Wu, wdec);
    k_edge_sorted<2><<<2048, 256, 0, stream>>>(srec, sdst, We, Wm, base_ws,
                                               nullptr, agg, outacc);
    k_final<<<384, 256, 0, stream>>>(outacc, vm, out);
}

// Round 5
// 167.149 us; speedup vs baseline: 1.2631x; 1.2631x over previous
//
#include <hip/hip_runtime.h>
#include <math.h>

#define NNODE 32768     // B*T*N
#define NEDGE 524288    // NNODE * DEG
#define DD 64           // feature dim D
#define EPS_G 65536     // edges per structure (NEDGE/8)

typedef float  f32x4 __attribute__((ext_vector_type(4)));
typedef short  s16x8 __attribute__((ext_vector_type(8)));

__device__ __forceinline__ float silu_f(float x) {
    return x / (1.0f + __expf(-x));
}
// f32 -> bf16 bits, round-to-nearest-even
__device__ __forceinline__ unsigned short bf16r(float f) {
    unsigned u = __float_as_uint(f);
    unsigned r = (u + 0x7FFFu + ((u >> 16) & 1u)) >> 16;
    return (unsigned short)r;
}

// pos = x * v_mask + x1 * (1 - v_mask)
__global__ __launch_bounds__(256) void k_prep(
    const float* __restrict__ x, const float* __restrict__ x1,
    const float* __restrict__ vm, float* __restrict__ pos)
{
    int i = blockIdx.x * 256 + threadIdx.x;      // 128 blocks
    float m = vm[i];
    #pragma unroll
    for (int c = 0; c < 3; ++c)
        pos[i*3+c] = x[i*3+c]*m + x1[i*3+c]*(1.0f-m);
}

// base vectors + pre-converted bf16 W3 fragments (B-frag layout for the edge MFMA).
// wm3[((t2*2+s)*64+lane)*8+j] = bf16(Wm[(128 + s*32 + (lane>>4)*8 + j)*64 + t2*16+(lane&15)])
__global__ __launch_bounds__(256) void k_base(
    const float* __restrict__ Wsp, const float* __restrict__ Wt,
    const float* __restrict__ Wm, const float* __restrict__ tarr,
    float* __restrict__ base_ws, unsigned short* __restrict__ wm3)
{
    int tid = threadIdx.x;
    if (tid < 64) {
        float t0 = tarr[0], t1 = tarr[1];
        float aA = 0.0f, aB = 0.0f;
        for (int k = 0; k < DD; ++k) {
            float w = Wm[k*DD + tid] + Wm[(DD+k)*DD + tid];
            aA = fmaf(Wsp[k] + t0*Wt[k], w, aA);
            aB = fmaf(Wsp[k] + t1*Wt[k], w, aB);
        }
        base_ws[tid]      = aA;
        base_ws[DD + tid] = aB;
    }
    for (int idx = tid; idx < 4096; idx += 256) {
        int j  = idx & 7;
        int ln = (idx >> 3) & 63;
        int ts = idx >> 9;            // t2*2+s
        int t2 = ts >> 1, s = ts & 1;
        int k   = s*32 + (ln >> 4)*8 + j;
        int col = t2*16 + (ln & 15);
        wm3[idx] = bf16r(Wm[(128 + k)*DD + col]);
    }
}

// histogram of dst (cnt pre-zeroed by memset)
__global__ __launch_bounds__(256) void k_hist(
    const int* __restrict__ ei, int* __restrict__ cnt)
{
    int g = blockIdx.x & 7;
    int e = g * EPS_G + (blockIdx.x >> 3) * 256 + threadIdx.x;  // 2048 blocks
    atomicAdd(&cnt[ei[NEDGE + e]], 1);
}

// exclusive scan of cnt[32768] -> cursor[32768]. One block, 1024 threads.
__global__ __launch_bounds__(1024) void k_scan(
    const int* __restrict__ cnt, int* __restrict__ cursor)
{
    __shared__ int buf[2][1024];
    const int tid = threadIdx.x;
    const int base = tid * 32;
    int loc[32];
    int s = 0;
    #pragma unroll
    for (int j = 0; j < 32; ++j) { int c = cnt[base+j]; loc[j] = c; s += c; }
    buf[0][tid] = s;
    __syncthreads();
    int pp = 0;
    for (int off = 1; off < 1024; off <<= 1) {
        int v = buf[pp][tid];
        if (tid >= off) v += buf[pp][tid - off];
        buf[pp^1][tid] = v;
        __syncthreads();
        pp ^= 1;
    }
    int ex = tid ? buf[pp][tid-1] : 0;
    #pragma unroll
    for (int j = 0; j < 32; ++j) { cursor[base+j] = ex; ex += loc[j]; }
}

// compute geometry once + counting-sort scatter by dst.
__global__ __launch_bounds__(256) void k_sortgeo(
    const int* __restrict__ ei, const int* __restrict__ tj,
    const float* __restrict__ pos, const float* __restrict__ cell,
    int* __restrict__ cursor, float4* __restrict__ srec, int* __restrict__ sdst)
{
    int g = blockIdx.x & 7;
    int e = g * EPS_G + (blockIdx.x >> 3) * 256 + threadIdx.x;  // 2048 blocks
    int src = ei[e];
    int dst = ei[NEDGE + e];
    const float* cl = cell + g*9;
    float c00=cl[0],c01=cl[1],c02=cl[2],c10=cl[3],c11=cl[4],c12=cl[5],c20=cl[6],c21=cl[7],c22=cl[8];
    float tj0 = (float)tj[e*3+0], tj1 = (float)tj[e*3+1], tj2 = (float)tj[e*3+2];
    float ev0 = pos[dst*3+0] - pos[src*3+0] + tj0*c00 + tj1*c10 + tj2*c20;
    float ev1 = pos[dst*3+1] - pos[src*3+1] + tj0*c01 + tj1*c11 + tj2*c21;
    float ev2 = pos[dst*3+2] - pos[src*3+2] + tj0*c02 + tj1*c12 + tj2*c22;
    float len = sqrtf(ev0*ev0 + ev1*ev1 + ev2*ev2 + 1e-12f);
    int slot = atomicAdd(&cursor[dst], 1);
    srec[slot] = (float4){ev0, ev1, ev2, len};
    sdst[slot] = dst;
}

// Single fused edge pass on dst-sorted edges. One wave per 64-thread block,
// 2 contiguous 64-edge tiles per wave. Segmented-reduce 4 planes per run:
//   agg[n][d]  += msg[d]
//   v[n][c][d] += ev[c]*msg[d]   (c=0..2)
__global__ __launch_bounds__(64) void k_edge_fused(
    const float4* __restrict__ srec, const int* __restrict__ sdst,
    const unsigned short* __restrict__ wm3,
    const float* __restrict__ We, const float* __restrict__ base_ws,
    float* agg, float* vbuf)
{
    const int lane = threadIdx.x;
    const int lo16 = lane & 15;
    const int hi   = lane >> 4;
    const int g    = blockIdx.x & 7;          // structure (XCD slot)
    const int widx = blockIdx.x >> 3;         // 0..511
    const int e0   = g * EPS_G + widx * 128;  // 128 contiguous sorted edges

    // LDS: edge4 f4[64] @0 | dstl int[64] @1024 | ea bf16[16][72] @1280 | msg f32[16][65] @3584
    __shared__ __align__(16) char my[7744];
    float4*         edge4  = (float4*)my;
    int*            dstl   = (int*)(my + 1024);
    unsigned short* ealds  = (unsigned short*)(my + 1280);
    float*          msglds = (float*)(my + 3584);

    // weights: pre-converted bf16 fragments (8 coalesced 16B loads)
    s16x8 bfr[4][2];
    #pragma unroll
    for (int t2 = 0; t2 < 4; ++t2)
        #pragma unroll
        for (int s = 0; s < 2; ++s)
            bfr[t2][s] = *(const s16x8*)(wm3 + ((t2*2+s)*64 + lane)*8);
    const float we0 = We[0*DD+lane], we1 = We[1*DD+lane];
    const float we2 = We[2*DD+lane], we3 = We[3*DD+lane];
    const bool  sb  = (g >> 2) != 0;
    const float bv0 = base_ws[sb*DD + 0*16+lo16];
    const float bv1 = base_ws[sb*DD + 1*16+lo16];
    const float bv2 = base_ws[sb*DD + 2*16+lo16];
    const float bv3 = base_ws[sb*DD + 3*16+lo16];

    // run-carry state (lane = channel d)
    int   curn = -1;
    float s0 = 0.f, sv0 = 0.f, sv1 = 0.f, sv2 = 0.f;

    #pragma unroll
    for (int tt = 0; tt < 2; ++tt) {
        __syncthreads();                      // prior segreduce reads of edge4 done
        const int eb = e0 + tt*64;
        edge4[lane] = srec[eb + lane];
        dstl[lane]  = sdst[eb + lane];

        #pragma unroll
        for (int i = 0; i < 4; ++i) {
            __syncthreads();                  // edge4/dstl visible; msglds reusable
            #pragma unroll
            for (int ee = 0; ee < 16; ++ee) {
                float4 q = edge4[i*16 + ee];  // uniform -> broadcast
                float v = q.x*we0 + q.y*we1 + q.z*we2 + q.w*we3;
                ealds[ee*72 + lane] = bf16r(silu_f(v));
            }
            __syncthreads();                  // ea tile visible

            const unsigned short* arow = ealds + lo16*72 + hi*8;
            s16x8 a0 = *(const s16x8*)(arow);
            s16x8 a1 = *(const s16x8*)(arow + 32);
            #pragma unroll
            for (int t2 = 0; t2 < 4; ++t2) {
                f32x4 acc = {0.f, 0.f, 0.f, 0.f};
                acc = __builtin_amdgcn_mfma_f32_16x16x32_bf16(a0, bfr[t2][0], acc, 0, 0, 0);
                acc = __builtin_amdgcn_mfma_f32_16x16x32_bf16(a1, bfr[t2][1], acc, 0, 0, 0);
                const float bvt = t2==0 ? bv0 : t2==1 ? bv1 : t2==2 ? bv2 : bv3;
                #pragma unroll
                for (int r = 0; r < 4; ++r)
                    msglds[(hi*4+r)*65 + t2*16 + lo16] = silu_f(acc[r] + bvt);
            }
            __syncthreads();                  // msg tile visible

            // segmented reduce (lane = channel); run carried across subtiles/tiles
            #pragma unroll
            for (int r = 0; r < 16; ++r) {
                int nd = dstl[i*16 + r];      // uniform broadcast
                if (nd != curn) {             // wave-uniform branch
                    if (curn >= 0) {
                        atomicAdd(&agg[curn*DD + lane], s0);
                        atomicAdd(&vbuf[(curn*3+0)*DD + lane], sv0);
                        atomicAdd(&vbuf[(curn*3+1)*DD + lane], sv1);
                        atomicAdd(&vbuf[(curn*3+2)*DD + lane], sv2);
                    }
                    s0 = sv0 = sv1 = sv2 = 0.f;
                    curn = nd;
                }
                float m  = msglds[r*65 + lane];
                float4 q = edge4[i*16 + r];
                s0 += m;
                sv0 = fmaf(q.x, m, sv0);
                sv1 = fmaf(q.y, m, sv1);
                sv2 = fmaf(q.z, m, sv2);
            }
        }
    }
    if (curn >= 0) {
        atomicAdd(&agg[curn*DD + lane], s0);
        atomicAdd(&vbuf[(curn*3+0)*DD + lane], sv0);
        atomicAdd(&vbuf[(curn*3+1)*DD + lane], sv1);
        atomicAdd(&vbuf[(curn*3+2)*DD + lane], sv2);
    }
}

// Gate + readout: g[d]=silu(h+silu(agg@Wu))*wdec;  out[n][c] = vm[n]*sum_d v[n][c][d]*g[d]
__global__ __launch_bounds__(256) void k_node(
    const float* __restrict__ agg, const float* __restrict__ vbuf,
    const float* __restrict__ vm,
    const float* __restrict__ t, const float* __restrict__ Wsp,
    const float* __restrict__ Wt, const float* __restrict__ Wu,
    const float* __restrict__ wdec, float* __restrict__ out)
{
    const int lane = threadIdx.x & 63;
    const int warp = threadIdx.x >> 6;
    const int g    = blockIdx.x & 7;
    const int wloc = (blockIdx.x >> 3) * 4 + warp;     // 0..1023 per structure

    float wu[DD];
    #pragma unroll
    for (int k = 0; k < DD; ++k) wu[k] = Wu[k*DD + lane];
    const float wsl = Wsp[lane], wtl = Wt[lane], wd = wdec[lane];
    const float tb = (g >> 2) == 0 ? t[0] : t[1];

    #pragma unroll
    for (int j = 0; j < 4; ++j) {
        int nd = g*4096 + wloc + j*1024;
        float a = agg[nd*DD + lane];
        unsigned ab = __float_as_uint(a);
        float acc = 0.0f;
        #pragma unroll
        for (int k = 0; k < DD; ++k) {
            float ak = __uint_as_float(__builtin_amdgcn_readlane(ab, k));
            acc = fmaf(ak, wu[k], acc);
        }
        float hn   = wsl + tb * wtl + silu_f(acc);
        float gate = silu_f(hn) * wd;

        float p0 = vbuf[(nd*3+0)*DD + lane] * gate;
        float p1 = vbuf[(nd*3+1)*DD + lane] * gate;
        float p2 = vbuf[(nd*3+2)*DD + lane] * gate;
        #pragma unroll
        for (int st = 1; st < 64; st <<= 1) {
            p0 += __shfl_xor(p0, st, 64);
            p1 += __shfl_xor(p1, st, 64);
            p2 += __shfl_xor(p2, st, 64);
        }
        float m = vm[nd];
        if (lane < 3)
            out[nd*3 + lane] = (lane==0 ? p0 : lane==1 ? p1 : p2) * m;
    }
}

extern "C" void kernel_launch(void* const* d_in, const int* in_sizes, int n_in,
                              void* d_out, int out_size, void* d_ws, size_t ws_size,
                              hipStream_t stream) {
    const float* x    = (const float*)d_in[0];
    const float* t    = (const float*)d_in[1];
    const float* cell = (const float*)d_in[2];
    const float* x1   = (const float*)d_in[3];
    const float* vm   = (const float*)d_in[4];
    const float* Wsp  = (const float*)d_in[5];
    const float* Wt   = (const float*)d_in[6];
    const float* We   = (const float*)d_in[7];
    const float* Wm   = (const float*)d_in[8];
    const float* Wu   = (const float*)d_in[9];
    const float* wdec = (const float*)d_in[10];
    const int*   ei   = (const int*)d_in[11];
    const int*   tj   = (const int*)d_in[12];
    float* out = (float*)d_out;

    // ws layout (float units):
    // srec[2097152] | vbuf[6291456] | agg[2097152] | pos[98304] | base[128]
    // wm3 (4096 ushort = 2048 f) | cnt[32768] | cursor[32768] | sdst[524288]
    float* ws      = (float*)d_ws;
    float4* srec   = (float4*)ws;                    // 16B-aligned at 0
    float* vbuf    = ws + 2097152;
    float* agg     = vbuf + 6291456;
    float* pos     = agg + 2097152;
    float* base_ws = pos + 98304;
    unsigned short* wm3 = (unsigned short*)(base_ws + 128);
    int*   cnt     = (int*)(base_ws + 128 + 2048);
    int*   cursor  = cnt + 32768;
    int*   sdst    = cursor + 32768;

    hipMemsetAsync(agg, 0, 2097152*sizeof(float), stream);
    hipMemsetAsync(vbuf, 0, 6291456*sizeof(float), stream);
    hipMemsetAsync(cnt, 0, 32768*sizeof(int), stream);

    k_prep<<<128, 256, 0, stream>>>(x, x1, vm, pos);
    k_base<<<1, 256, 0, stream>>>(Wsp, Wt, Wm, t, base_ws, wm3);
    k_hist<<<2048, 256, 0, stream>>>(ei, cnt);
    k_scan<<<1, 1024, 0, stream>>>(cnt, cursor);
    k_sortgeo<<<2048, 256, 0, stream>>>(ei, tj, pos, cell, cursor, srec, sdst);
    k_edge_fused<<<4096, 64, 0, stream>>>(srec, sdst, wm3, We, base_ws, agg, vbuf);
    k_node<<<2048, 256, 0, stream>>>(agg, vbuf, vm, t, Wsp, Wt, Wu, wdec, out);
}

// Round 6
// 156.049 us; speedup vs baseline: 1.3529x; 1.0711x over previous
//
#include <hip/hip_runtime.h>
#include <math.h>

#define NNODE 32768     // B*T*N
#define NEDGE 524288    // NNODE * DEG
#define DD 64           // feature dim D
#define EPS_G 65536     // edges per structure
#define NPS 4096        // nodes per structure

typedef float  f32x4 __attribute__((ext_vector_type(4)));
typedef short  s16x8 __attribute__((ext_vector_type(8)));

__device__ __forceinline__ float silu_f(float x) {
    return x / (1.0f + __expf(-x));
}
__device__ __forceinline__ unsigned short bf16r(float f) {
    unsigned u = __float_as_uint(f);
    unsigned r = (u + 0x7FFFu + ((u >> 16) & 1u)) >> 16;
    return (unsigned short)r;
}
__device__ __forceinline__ float bf16f(unsigned short u) {
    return __uint_as_float(((unsigned)u) << 16);
}

// fused: pos prep (nodes, first 128 blocks) + dst histogram/rank (edges, all blocks)
__global__ __launch_bounds__(256) void k_prep_hist(
    const float* __restrict__ x, const float* __restrict__ x1,
    const float* __restrict__ vm, float* __restrict__ pos,
    const int* __restrict__ ei, int* __restrict__ cnt, int* __restrict__ rank)
{
    int tid = threadIdx.x, b = blockIdx.x;          // 2048 blocks
    if (b < 128) {
        int i = b*256 + tid;
        float m = vm[i];
        #pragma unroll
        for (int c = 0; c < 3; ++c)
            pos[i*3+c] = x[i*3+c]*m + x1[i*3+c]*(1.0f-m);
    }
    int e = b*256 + tid;
    rank[e] = atomicAdd(&cnt[ei[NEDGE + e]], 1);
}

// base vectors + bf16 B-fragments for W_msg[128:192] (wfrag[0:4096]) and W_upd (wfrag[4096:8192])
__global__ __launch_bounds__(256) void k_base(
    const float* __restrict__ Wsp, const float* __restrict__ Wt,
    const float* __restrict__ Wm, const float* __restrict__ Wu,
    const float* __restrict__ tarr,
    float* __restrict__ base_ws, unsigned short* __restrict__ wfrag)
{
    int tid = threadIdx.x;
    if (tid < 64) {
        float t0 = tarr[0], t1 = tarr[1];
        float aA = 0.0f, aB = 0.0f;
        for (int k = 0; k < DD; ++k) {
            float w = Wm[k*DD + tid] + Wm[(DD+k)*DD + tid];
            aA = fmaf(Wsp[k] + t0*Wt[k], w, aA);
            aB = fmaf(Wsp[k] + t1*Wt[k], w, aB);
        }
        base_ws[tid]      = aA;
        base_ws[DD + tid] = aB;
    }
    for (int idx = tid; idx < 8192; idx += 256) {
        int sel = idx >> 12, id2 = idx & 4095;
        int j  = id2 & 7;
        int ln = (id2 >> 3) & 63;
        int ts = id2 >> 9;
        int t2 = ts >> 1, s = ts & 1;
        int k   = s*32 + (ln >> 4)*8 + j;
        int col = t2*16 + (ln & 15);
        wfrag[idx] = bf16r(sel ? Wu[k*DD + col] : Wm[(128 + k)*DD + col]);
    }
}

// exclusive scan of cnt[32768] -> rowptr[0..32768]
__global__ __launch_bounds__(1024) void k_scan(
    const int* __restrict__ cnt, int* __restrict__ rowptr)
{
    __shared__ int buf[2][1024];
    const int tid = threadIdx.x;
    int4 L[8];
    int s = 0;
    #pragma unroll
    for (int j = 0; j < 8; ++j) {
        L[j] = ((const int4*)cnt)[tid*8 + j];
        s += L[j].x + L[j].y + L[j].z + L[j].w;
    }
    buf[0][tid] = s;
    __syncthreads();
    int pp = 0;
    for (int off = 1; off < 1024; off <<= 1) {
        int v = buf[pp][tid];
        if (tid >= off) v += buf[pp][tid - off];
        buf[pp^1][tid] = v;
        __syncthreads();
        pp ^= 1;
    }
    int ex = tid ? buf[pp][tid-1] : 0;
    #pragma unroll
    for (int j = 0; j < 8; ++j) {
        int4 o;
        o.x = ex; ex += L[j].x;
        o.y = ex; ex += L[j].y;
        o.z = ex; ex += L[j].z;
        o.w = ex; ex += L[j].w;
        ((int4*)rowptr)[tid*8 + j] = o;
    }
    if (tid == 1023) rowptr[32768] = NEDGE;
}

// geometry (coalesced rec[e] write) + permutation scatter perm[slot]=e
__global__ __launch_bounds__(256) void k_geo_perm(
    const int* __restrict__ ei, const int* __restrict__ tj,
    const float* __restrict__ pos, const float* __restrict__ cell,
    const int* __restrict__ rowptr, const int* __restrict__ rank,
    float4* __restrict__ rec, int* __restrict__ perm)
{
    int e = blockIdx.x * 256 + threadIdx.x;         // 2048 blocks
    int g = e >> 16;                                 // structure id
    int src = ei[e];
    int dst = ei[NEDGE + e];
    const float* cl = cell + g*9;
    float c00=cl[0],c01=cl[1],c02=cl[2],c10=cl[3],c11=cl[4],c12=cl[5],c20=cl[6],c21=cl[7],c22=cl[8];
    float tj0 = (float)tj[e*3+0], tj1 = (float)tj[e*3+1], tj2 = (float)tj[e*3+2];
    float ev0 = pos[dst*3+0] - pos[src*3+0] + tj0*c00 + tj1*c10 + tj2*c20;
    float ev1 = pos[dst*3+1] - pos[src*3+1] + tj0*c01 + tj1*c11 + tj2*c21;
    float ev2 = pos[dst*3+2] - pos[src*3+2] + tj0*c02 + tj1*c12 + tj2*c22;
    float len = sqrtf(ev0*ev0 + ev1*ev1 + ev2*ev2 + 1e-12f);
    rec[e] = (float4){ev0, ev1, ev2, len};
    perm[rowptr[dst] + rank[e]] = e;
}

// One wave per 8-node group: processes ALL edges of its nodes (CSR slice),
// accumulates agg/v per node in LDS (plain stores, exclusive ownership),
// then computes gate (Wu MFMA) + readout and writes out directly.
__global__ __launch_bounds__(64) void k_edge_all(
    const int* __restrict__ perm, const float4* __restrict__ rec,
    const int* __restrict__ ei, const int* __restrict__ rowptr,
    const unsigned short* __restrict__ wfrag,
    const float* __restrict__ We, const float* __restrict__ base_ws,
    const float* __restrict__ Wsp, const float* __restrict__ Wt,
    const float* __restrict__ wdec, const float* __restrict__ tarr,
    const float* __restrict__ vm, float* __restrict__ out)
{
    const int lane = threadIdx.x;
    const int lo16 = lane & 15;
    const int hi   = lane >> 4;
    const int g    = blockIdx.x & 7;          // structure == XCD slot
    const int widx = blockIdx.x >> 3;         // 0..511
    const int n0   = (g*512 + widx) * 8;      // first of 8 owned nodes

    // LDS: edge4 f4[64]@0 | dstl i32[64]@1024 | ealds u16[16][72]@1280 |
    //      msglds f32[16][65]@3584 | agg_l u16[16][72]@7744 | v_l u16[8][3][68]@10048
    __shared__ __align__(16) char my[13312];
    float4*         edge4  = (float4*)my;
    int*            dstl   = (int*)(my + 1024);
    unsigned short* ealds  = (unsigned short*)(my + 1280);
    float*          msglds = (float*)(my + 3584);
    unsigned short* agg_l  = (unsigned short*)(my + 7744);
    unsigned short* v_l    = (unsigned short*)(my + 10048);

    // zero agg_l + v_l (5568 B = 1392 words)
    {
        int* zp = (int*)(my + 7744);
        #pragma unroll
        for (int j = 0; j < 22; ++j) {
            int o = j*64 + lane;
            if (o < 1392) zp[o] = 0;
        }
    }

    // weight fragments
    s16x8 bfr[4][2], wub[4][2];
    #pragma unroll
    for (int t2 = 0; t2 < 4; ++t2)
        #pragma unroll
        for (int s = 0; s < 2; ++s) {
            bfr[t2][s] = *(const s16x8*)(wfrag + ((t2*2+s)*64 + lane)*8);
            wub[t2][s] = *(const s16x8*)(wfrag + 4096 + ((t2*2+s)*64 + lane)*8);
        }
    const float we0 = We[0*DD+lane], we1 = We[1*DD+lane];
    const float we2 = We[2*DD+lane], we3 = We[3*DD+lane];
    const bool  sb  = (g >> 2) != 0;
    const float bv0 = base_ws[sb*DD + 0*16+lo16];
    const float bv1 = base_ws[sb*DD + 1*16+lo16];
    const float bv2 = base_ws[sb*DD + 2*16+lo16];
    const float bv3 = base_ws[sb*DD + 3*16+lo16];
    const float tb  = sb ? tarr[1] : tarr[0];
    float hbw[4], wd4[4];
    #pragma unroll
    for (int t2 = 0; t2 < 4; ++t2) {
        hbw[t2] = Wsp[t2*16+lo16] + tb * Wt[t2*16+lo16];
        wd4[t2] = wdec[t2*16+lo16];
    }

    const int estart = rowptr[n0];
    const int eend   = rowptr[n0 + 8];
    const int* eid   = ei + NEDGE;

    int   curn = -1;
    float s0 = 0.f, sva = 0.f, svb = 0.f, svc = 0.f;

    for (int ebase = estart; ebase < eend; ebase += 64) {
        int cnt64 = eend - ebase; if (cnt64 > 64) cnt64 = 64;
        __syncthreads();                       // edge4/dstl readers done
        int ii   = ebase + (lane < cnt64 ? lane : cnt64 - 1);
        int pidx = perm[ii];
        edge4[lane] = rec[pidx];               // L2-local gather
        dstl[lane]  = eid[pidx];
        __syncthreads();

        int nsub = (cnt64 + 15) >> 4;
        for (int i = 0; i < nsub; ++i) {
            #pragma unroll
            for (int ee = 0; ee < 16; ++ee) {
                float4 q = edge4[i*16 + ee];   // uniform broadcast
                float v = q.x*we0 + q.y*we1 + q.z*we2 + q.w*we3;
                ealds[ee*72 + lane] = bf16r(silu_f(v));
            }
            __syncthreads();                   // ea tile visible

            const unsigned short* arow = ealds + lo16*72 + hi*8;
            s16x8 a0 = *(const s16x8*)(arow);
            s16x8 a1 = *(const s16x8*)(arow + 32);
            #pragma unroll
            for (int t2 = 0; t2 < 4; ++t2) {
                f32x4 acc = {0.f, 0.f, 0.f, 0.f};
                acc = __builtin_amdgcn_mfma_f32_16x16x32_bf16(a0, bfr[t2][0], acc, 0, 0, 0);
                acc = __builtin_amdgcn_mfma_f32_16x16x32_bf16(a1, bfr[t2][1], acc, 0, 0, 0);
                const float bvt = t2==0 ? bv0 : t2==1 ? bv1 : t2==2 ? bv2 : bv3;
                #pragma unroll
                for (int r = 0; r < 4; ++r)
                    msglds[(hi*4+r)*65 + t2*16 + lo16] = silu_f(acc[r] + bvt);
            }
            __syncthreads();                   // msg tile visible

            int rows = cnt64 - i*16; if (rows > 16) rows = 16;
            for (int r = 0; r < rows; ++r) {
                int nd = dstl[i*16 + r];       // uniform
                if (nd != curn) {              // wave-uniform branch
                    if (curn >= 0) {
                        int nl = curn - n0;
                        agg_l[nl*72 + lane]       = bf16r(s0);
                        v_l[(nl*3+0)*68 + lane]   = bf16r(sva);
                        v_l[(nl*3+1)*68 + lane]   = bf16r(svb);
                        v_l[(nl*3+2)*68 + lane]   = bf16r(svc);
                    }
                    s0 = sva = svb = svc = 0.f;
                    curn = nd;
                }
                float  m = msglds[r*65 + lane];
                float4 q = edge4[i*16 + r];
                s0 += m;
                sva = fmaf(q.x, m, sva);
                svb = fmaf(q.y, m, svb);
                svc = fmaf(q.z, m, svc);
            }
            __syncthreads();                   // seg reads done before next stage
        }
    }
    if (curn >= 0) {
        int nl = curn - n0;
        agg_l[nl*72 + lane]     = bf16r(s0);
        v_l[(nl*3+0)*68 + lane] = bf16r(sva);
        v_l[(nl*3+1)*68 + lane] = bf16r(svb);
        v_l[(nl*3+2)*68 + lane] = bf16r(svc);
    }
    __syncthreads();

    // ---- node phase: gate = silu(h + silu(agg@Wu)) * wdec; out = vm * (v . gate) ----
    const unsigned short* ar = agg_l + lo16*72 + hi*8;   // A: row=node(lo16), k=hi*8+j
    s16x8 ga0 = *(const s16x8*)(ar);
    s16x8 ga1 = *(const s16x8*)(ar + 32);
    float p[4][3] = {{0.f,0.f,0.f},{0.f,0.f,0.f},{0.f,0.f,0.f},{0.f,0.f,0.f}};
    #pragma unroll
    for (int t2 = 0; t2 < 4; ++t2) {
        f32x4 accg = {0.f, 0.f, 0.f, 0.f};
        accg = __builtin_amdgcn_mfma_f32_16x16x32_bf16(ga0, wub[t2][0], accg, 0, 0, 0);
        accg = __builtin_amdgcn_mfma_f32_16x16x32_bf16(ga1, wub[t2][1], accg, 0, 0, 0);
        #pragma unroll
        for (int r = 0; r < 4; ++r) {
            int node = hi*4 + r;               // D: col=outch(lo16 within t2), row=node
            float hn   = hbw[t2] + silu_f(accg[r]);
            float gate = silu_f(hn) * wd4[t2];
            if (node < 8) {
                #pragma unroll
                for (int c = 0; c < 3; ++c) {
                    float vv = bf16f(v_l[(node*3+c)*68 + t2*16 + lo16]);
                    p[r][c] = fmaf(gate, vv, p[r][c]);
                }
            }
        }
    }
    #pragma unroll
    for (int st = 1; st < 16; st <<= 1)
        #pragma unroll
        for (int r = 0; r < 4; ++r)
            #pragma unroll
            for (int c = 0; c < 3; ++c)
                p[r][c] += __shfl_xor(p[r][c], st, 64);

    if (lo16 < 12 && hi < 2) {
        int rr = lo16 / 3, c = lo16 - rr*3;
        float val = rr==0 ? (c==0 ? p[0][0] : c==1 ? p[0][1] : p[0][2])
                  : rr==1 ? (c==0 ? p[1][0] : c==1 ? p[1][1] : p[1][2])
                  : rr==2 ? (c==0 ? p[2][0] : c==1 ? p[2][1] : p[2][2])
                  :         (c==0 ? p[3][0] : c==1 ? p[3][1] : p[3][2]);
        int node = hi*4 + rr;
        out[(n0 + node)*3 + c] = val * vm[n0 + node];
    }
}

extern "C" void kernel_launch(void* const* d_in, const int* in_sizes, int n_in,
                              void* d_out, int out_size, void* d_ws, size_t ws_size,
                              hipStream_t stream) {
    const float* x    = (const float*)d_in[0];
    const float* t    = (const float*)d_in[1];
    const float* cell = (const float*)d_in[2];
    const float* x1   = (const float*)d_in[3];
    const float* vm   = (const float*)d_in[4];
    const float* Wsp  = (const float*)d_in[5];
    const float* Wt   = (const float*)d_in[6];
    const float* We   = (const float*)d_in[7];
    const float* Wm   = (const float*)d_in[8];
    const float* Wu   = (const float*)d_in[9];
    const float* wdec = (const float*)d_in[10];
    const int*   ei   = (const int*)d_in[11];
    const int*   tj   = (const int*)d_in[12];
    float* out = (float*)d_out;

    // ws layout (float units):
    // rec[2097152] | pos[98304] | rank[524288] | perm[524288] |
    // rowptr[32784 pad] | cnt[32768] | base[128] | wfrag(8192 u16 = 4096 f)
    float*  ws      = (float*)d_ws;
    float4* rec     = (float4*)ws;
    float*  pos     = ws + 2097152;
    int*    rank    = (int*)(pos + 98304);
    int*    perm    = rank + 524288;
    int*    rowptr  = perm + 524288;
    int*    cnt     = rowptr + 32784;
    float*  base_ws = (float*)(cnt + 32768);
    unsigned short* wfrag = (unsigned short*)(base_ws + 128);

    hipMemsetAsync(cnt, 0, 32768*sizeof(int), stream);
    k_prep_hist<<<2048, 256, 0, stream>>>(x, x1, vm, pos, ei, cnt, rank);
    k_base<<<1, 256, 0, stream>>>(Wsp, Wt, Wm, Wu, t, base_ws, wfrag);
    k_scan<<<1, 1024, 0, stream>>>(cnt, rowptr);
    k_geo_perm<<<2048, 256, 0, stream>>>(ei, tj, pos, cell, rowptr, rank, rec, perm);
    k_edge_all<<<4096, 64, 0, stream>>>(perm, rec, ei, rowptr, wfrag, We, base_ws,
                                        Wsp, Wt, wdec, t, vm, out);
}